// Round 1
// 219.559 us; speedup vs baseline: 1.0196x; 1.0196x over previous
//
#include <hip/hip_runtime.h>

typedef _Float16 f16x8 __attribute__((ext_vector_type(8)));
typedef float f32x4 __attribute__((ext_vector_type(4)));
typedef unsigned short u16;
typedef u16 u16x8 __attribute__((ext_vector_type(8)));
typedef u16 u16x4 __attribute__((ext_vector_type(4)));

// ---------- fp16 <-> fp32 helpers ----------
__device__ __forceinline__ u16 f2h_bits(float f) {
    _Float16 h = (_Float16)f;           // RNE
    return __builtin_bit_cast(u16, h);
}
__device__ __forceinline__ float h2f(u16 b) {
    return (float)__builtin_bit_cast(_Float16, b);
}

// async global->LDS, 16B per lane. LDS dest is wave-uniform base + lane*16;
// we pass per-thread t*16 which is exactly that layout.
typedef __attribute__((address_space(1))) unsigned int gu32_as1;
typedef __attribute__((address_space(3))) unsigned int lu32_as3;
__device__ __forceinline__ void gload16(const u16* g, u16* l) {
    __builtin_amdgcn_global_load_lds((gu32_as1*)g, (lu32_as3*)l, 16, 0, 0);
}

// =====================================================================
// GEMM: C[M,N] = alpha * A[M,K] * Bt[N,K]^T  (fp16 bits, k-contiguous).
//
// 256x256 tile, BK=64, 512 threads = 8 waves (2M x 4N), each wave owns a
// 128x64 C-tile = acc[8][4] f32x4 via mfma_f32_16x16x32_f16.
//
// 8-phase schedule (4 phases per K-tile, 2 K-tiles in flight):
//   P1: ds_read A(mh0)+B(nh0)                 -> MFMA quadrant (0,0)
//   P2: ds_read B(nh1)                        -> MFMA quadrant (0,1)
//   P3: ds_read A(mh1); STAGE B(t+2)          -> MFMA quadrant (1,0)
//   P4:              STAGE A(t+2)             -> MFMA quadrant (1,1)
//   each phase: {reads|stage} ; barrier ; setprio(1) 16xMFMA setprio(0) ; barrier
//   counted s_waitcnt vmcnt(8) once per K-tile (vmcnt(0) only at tile NT-2).
// Region-death proof: B halves are fully read by end of P2 (lgkmcnt before
// P2 MFMA, published by P2 post-barrier) -> staging B(t+2) at P3 is safe;
// A halves fully read by end of P3 -> staging A(t+2) at P4 is safe.
//
// LDS (128 KiB): per matrix [buf:2][half:2][seg-grp i:2][row:128][slot:4][8]
// u16 strides: buf 16384, half 8192, i 4096, row 32, slot 8.
// Swizzle (proven 0-conflict): slot s' at row r holds global seg
// s'^((r>>1)&3) (+4i). global_load_lds writes linearly at t*8 u16; the
// per-lane GLOBAL address is pre-swizzled: seg = (t&3)^((t>>3)&3) (+4i).
// Fragment read: row l16 (+16*mi), slot quad^((l16>>1)&3), region kk.
//
// MODE: 0 plain store; 1 exp(alpha*s)+rowsum atomics; 2 QKV (bn<8 -> QK
// ldc=2048; bn>=8 -> V transposed into vt[1024][4096]).
// Requires Ksplit % 64 == 0, Ksplit/64 >= 2. gridDim.z = split-K.
// =====================================================================
template <int MODE>
__global__ __launch_bounds__(512, 2) void gemm_bt(
    const u16* __restrict__ A, int lda,
    const u16* __restrict__ B, int ldb,
    u16* __restrict__ C, int ldc,
    int Ksplit, float alpha, size_t c_z_stride,
    int bnW, int bmW, int numPanelX,
    float* __restrict__ rowsum, u16* __restrict__ vt)
{
    __shared__ __attribute__((aligned(16))) u16 As[32768];  // 64 KB
    __shared__ __attribute__((aligned(16))) u16 Bs[32768];  // 64 KB

    const int t    = threadIdx.x;        // 0..511
    const int lane = t & 63;
    const int wave = t >> 6;             // 0..7
    const int wm   = wave >> 2;          // 0..1
    const int wn   = wave & 3;           // 0..3
    const int l16  = lane & 15;
    const int quad = lane >> 4;

    // 2D-panel XCD mapping (grid x*y divisible by 8)
    const int lin = blockIdx.y * gridDim.x + blockIdx.x;
    const int xcd = lin & 7;
    const int idx = lin >> 3;
    const int px  = xcd % numPanelX;
    const int py  = xcd / numPanelX;
    const int bn  = px * bnW + idx % bnW;
    const int bm  = py * bmW + idx / bnW;

    const int kz = blockIdx.z;
    A += (size_t)kz * Ksplit;
    B += (size_t)kz * Ksplit;
    C += (size_t)kz * c_z_stride;

    // staging: thread t -> row t>>2 of each 128-row half, LDS slot t&3,
    // global seg pre-swizzled so the linear LDS write lands swizzled.
    const int srow = t >> 2;
    const int sseg = (t & 3) ^ ((t >> 3) & 3);

    const u16* gA = A + (size_t)(bm * 256 + srow) * lda + sseg * 8;
    const u16* gB = B + (size_t)(bn * 256 + srow) * ldb + sseg * 8;
    const size_t a128 = (size_t)128 * lda;
    const size_t b128 = (size_t)128 * ldb;

    u16* lA = As + t * 8;
    u16* lB = Bs + t * 8;

#define STAGE_A(bufv, kt) do {                                   \
        const u16* _g = gA + (size_t)(kt) * 64;                  \
        u16* _l = lA + (bufv) * 16384;                           \
        gload16(_g,             _l);                             \
        gload16(_g + 32,        _l + 4096);                      \
        gload16(_g + a128,      _l + 8192);                      \
        gload16(_g + a128 + 32, _l + 12288);                     \
    } while (0)
#define STAGE_B(bufv, kt) do {                                   \
        const u16* _g = gB + (size_t)(kt) * 64;                  \
        u16* _l = lB + (bufv) * 16384;                           \
        gload16(_g,             _l);                             \
        gload16(_g + 32,        _l + 4096);                      \
        gload16(_g + b128,      _l + 8192);                      \
        gload16(_g + b128 + 32, _l + 12288);                     \
    } while (0)

    // fragment base pointers
    const int fslot = quad ^ ((l16 >> 1) & 3);
    const u16* Afr = As + wm * 8192 + l16 * 32 + fslot * 8;
    const u16* Bfr = Bs + (wn >> 1) * 8192 + (wn & 1) * 2048 + l16 * 32 + fslot * 8;

    f32x4 acc[8][4] = {};

    const int NT = Ksplit >> 6;

    // prologue: stage tiles 0 and 1 (8 loads each), wait for tile 0 only
    STAGE_A(0, 0); STAGE_B(0, 0);
    STAGE_A(1, 1); STAGE_B(1, 1);
    asm volatile("s_waitcnt vmcnt(8)" ::: "memory");
    __builtin_amdgcn_sched_barrier(0);
    __builtin_amdgcn_s_barrier();

    int buf = 0;
    for (int kt = 0; kt < NT; ++kt, buf ^= 1) {
        const u16* Af = Afr + buf * 16384;
        const u16* Bf = Bfr + buf * 16384;
        f16x8 af[4][2], bfA[2][2], bfB[2][2];

        // ---------------- P1: A(mh0)+B(nh0) reads; MFMA Q(0,0) ----------------
#pragma unroll
        for (int mi = 0; mi < 4; mi++)
#pragma unroll
            for (int kk = 0; kk < 2; kk++)
                af[mi][kk] = *(const f16x8*)(Af + kk * 4096 + mi * 512);
#pragma unroll
        for (int nj = 0; nj < 2; nj++)
#pragma unroll
            for (int kk = 0; kk < 2; kk++)
                bfA[nj][kk] = *(const f16x8*)(Bf + kk * 4096 + nj * 512);
        __builtin_amdgcn_sched_barrier(0);
        __builtin_amdgcn_s_barrier();
        __builtin_amdgcn_s_setprio(1);
#pragma unroll
        for (int mi = 0; mi < 4; mi++)
#pragma unroll
            for (int nj = 0; nj < 2; nj++)
#pragma unroll
                for (int kk = 0; kk < 2; kk++)
                    acc[mi][nj] = __builtin_amdgcn_mfma_f32_16x16x32_f16(
                        af[mi][kk], bfA[nj][kk], acc[mi][nj], 0, 0, 0);
        __builtin_amdgcn_s_setprio(0);
        __builtin_amdgcn_sched_barrier(0);
        __builtin_amdgcn_s_barrier();

        // ---------------- P2: B(nh1) reads; MFMA Q(0,1) ----------------
#pragma unroll
        for (int nj = 0; nj < 2; nj++)
#pragma unroll
            for (int kk = 0; kk < 2; kk++)
                bfB[nj][kk] = *(const f16x8*)(Bf + kk * 4096 + (2 + nj) * 512);
        __builtin_amdgcn_sched_barrier(0);
        __builtin_amdgcn_s_barrier();
        __builtin_amdgcn_s_setprio(1);
#pragma unroll
        for (int mi = 0; mi < 4; mi++)
#pragma unroll
            for (int nj = 0; nj < 2; nj++)
#pragma unroll
                for (int kk = 0; kk < 2; kk++)
                    acc[mi][2 + nj] = __builtin_amdgcn_mfma_f32_16x16x32_f16(
                        af[mi][kk], bfB[nj][kk], acc[mi][2 + nj], 0, 0, 0);
        __builtin_amdgcn_s_setprio(0);
        __builtin_amdgcn_sched_barrier(0);
        __builtin_amdgcn_s_barrier();

        // ------------ P3: A(mh1) reads; stage B(kt+2); MFMA Q(1,0) ------------
#pragma unroll
        for (int mi = 0; mi < 4; mi++)
#pragma unroll
            for (int kk = 0; kk < 2; kk++)
                af[mi][kk] = *(const f16x8*)(Af + kk * 4096 + (4 + mi) * 512);
        if (kt + 2 < NT) STAGE_B(buf, kt + 2);
        __builtin_amdgcn_sched_barrier(0);
        __builtin_amdgcn_s_barrier();
        __builtin_amdgcn_s_setprio(1);
#pragma unroll
        for (int mi = 0; mi < 4; mi++)
#pragma unroll
            for (int nj = 0; nj < 2; nj++)
#pragma unroll
                for (int kk = 0; kk < 2; kk++)
                    acc[4 + mi][nj] = __builtin_amdgcn_mfma_f32_16x16x32_f16(
                        af[mi][kk], bfA[nj][kk], acc[4 + mi][nj], 0, 0, 0);
        __builtin_amdgcn_s_setprio(0);
        __builtin_amdgcn_sched_barrier(0);
        __builtin_amdgcn_s_barrier();

        // ------------ P4: stage A(kt+2); MFMA Q(1,1); counted vmcnt ------------
        if (kt + 2 < NT) STAGE_A(buf, kt + 2);
        __builtin_amdgcn_sched_barrier(0);
        __builtin_amdgcn_s_barrier();
        __builtin_amdgcn_s_setprio(1);
#pragma unroll
        for (int mi = 0; mi < 4; mi++)
#pragma unroll
            for (int nj = 0; nj < 2; nj++)
#pragma unroll
                for (int kk = 0; kk < 2; kk++)
                    acc[4 + mi][2 + nj] = __builtin_amdgcn_mfma_f32_16x16x32_f16(
                        af[mi][kk], bfB[nj][kk], acc[4 + mi][2 + nj], 0, 0, 0);
        __builtin_amdgcn_s_setprio(0);
        // force tile kt+1's 8 loads complete; leave kt+2's 8 in flight
        if (kt < NT - 2)       asm volatile("s_waitcnt vmcnt(8)" ::: "memory");
        else if (kt == NT - 2) asm volatile("s_waitcnt vmcnt(0)" ::: "memory");
        __builtin_amdgcn_sched_barrier(0);
        __builtin_amdgcn_s_barrier();
    }
#undef STAGE_A
#undef STAGE_B

    // epilogue: C/D layout col = lane&15, row = quad*4 + reg
    const int crow = bm * 256 + wm * 128 + quad * 4;
    const int ccol = bn * 256 + wn * 64 + l16;

    if (MODE == 1) {
        float rs[8][4];
#pragma unroll
        for (int mi = 0; mi < 8; mi++)
#pragma unroll
            for (int r = 0; r < 4; r++) rs[mi][r] = 0.f;
#pragma unroll
        for (int mi = 0; mi < 8; mi++) {
#pragma unroll
            for (int ni = 0; ni < 4; ni++) {
#pragma unroll
                for (int r = 0; r < 4; r++) {
                    float e = __expf(acc[mi][ni][r] * alpha);
                    rs[mi][r] += e;
                    C[(size_t)(crow + mi * 16 + r) * ldc + (ccol + ni * 16)] = f2h_bits(e);
                }
            }
        }
#pragma unroll
        for (int mi = 0; mi < 8; mi++) {
#pragma unroll
            for (int r = 0; r < 4; r++) {
                float s = rs[mi][r];
#pragma unroll
                for (int o = 1; o < 16; o <<= 1) s += __shfl_xor(s, o);
                if (l16 == 0)
                    atomicAdd(&rowsum[crow + mi * 16 + r], s);
            }
        }
    } else if (MODE == 2 && bn >= 8) {
        // V tile -> write transposed into vt[1024][4096]
#pragma unroll
        for (int ni = 0; ni < 4; ni++) {
            const int cV = (bn - 8) * 256 + wn * 64 + ni * 16 + l16;
#pragma unroll
            for (int mi = 0; mi < 8; mi++) {
                u16x4 o;
#pragma unroll
                for (int r = 0; r < 4; r++) o[r] = f2h_bits(acc[mi][ni][r]);
                *(u16x4*)(vt + (size_t)cV * 4096 + crow + mi * 16) = o;
            }
        }
    } else {
#pragma unroll
        for (int mi = 0; mi < 8; mi++)
#pragma unroll
            for (int ni = 0; ni < 4; ni++)
#pragma unroll
                for (int r = 0; r < 4; r++)
                    C[(size_t)(crow + mi * 16 + r) * ldc + (ccol + ni * 16)] =
                        f2h_bits(acc[mi][ni][r] * alpha);
    }
}

// =====================================================================
// cast fp32 -> fp16 bits, 4 elems/thread
// =====================================================================
__global__ __launch_bounds__(256) void cast_to_f16(
    const float* __restrict__ in, u16* __restrict__ out, int n)
{
    int i = (blockIdx.x * 256 + threadIdx.x) * 4;
    if (i + 3 < n) {
        float4 v = *(const float4*)(in + i);
        ushort4 o;
        o.x = f2h_bits(v.x);
        o.y = f2h_bits(v.y);
        o.z = f2h_bits(v.z);
        o.w = f2h_bits(v.w);
        *(ushort4*)(out + i) = o;
    }
}

// =====================================================================
// transpose the 3 weight matrices [1024][1024] fp32 -> packed fp16
// Wt[3072][1024]; z selects the matrix. 32x32 LDS tile, block (32,8).
// =====================================================================
__global__ __launch_bounds__(256) void transpose_w3(
    const float* __restrict__ W0, const float* __restrict__ W1,
    const float* __restrict__ W2, u16* __restrict__ out)
{
    const float* in = (blockIdx.z == 0) ? W0 : (blockIdx.z == 1) ? W1 : W2;
    u16* o = out + (size_t)blockIdx.z * 1024 * 1024;
    __shared__ float tile[32][33];
    const int bx = blockIdx.x * 32;
    const int by = blockIdx.y * 32;
    const int tx = threadIdx.x, ty = threadIdx.y;
#pragma unroll
    for (int j = 0; j < 4; j++)
        tile[ty + j * 8][tx] = in[(size_t)(by + ty + j * 8) * 1024 + bx + tx];
    __syncthreads();
#pragma unroll
    for (int j = 0; j < 4; j++)
        o[(size_t)(bx + ty + j * 8) * 1024 + by + tx] = f2h_bits(tile[tx][ty + j * 8]);
}

// =====================================================================
// zero a float array (n multiple of 1024)
// =====================================================================
__global__ __launch_bounds__(256) void zero_f32(float* __restrict__ p, int n)
{
    int i = (blockIdx.x * 256 + threadIdx.x) * 4;
    if (i + 3 < n) *(float4*)(p + i) = float4{0.f, 0.f, 0.f, 0.f};
}

// =====================================================================
// out = (P0+P1+P2+P3)/l[row]; partials fp16, 8 elems/thread
// =====================================================================
__global__ __launch_bounds__(256) void add_div4(
    const u16* __restrict__ P, const float* __restrict__ l,
    float* __restrict__ o)
{
    const size_t zs = (size_t)4096 * 1024;
    int i = (blockIdx.x * 256 + threadIdx.x) * 8;
    float inv = 1.0f / l[i >> 10];
    float s[8] = {};
#pragma unroll
    for (int z = 0; z < 4; z++) {
        u16x8 h = *(const u16x8*)(P + z * zs + i);
#pragma unroll
        for (int j = 0; j < 8; j++) s[j] += h2f(h[j]);
    }
    float4 lo{s[0] * inv, s[1] * inv, s[2] * inv, s[3] * inv};
    float4 hi{s[4] * inv, s[5] * inv, s[6] * inv, s[7] * inv};
    *(float4*)(o + i) = lo;
    *(float4*)(o + i + 4) = hi;
}

// =====================================================================
// launch
//
// Workspace liveness (MiB):
//   xb [0,8)    live 1-3          Wt [8,14)  live 2-3
//   QK [14,30)  live 3-5          Vt [64,72) live 3-6
//   Sb [32,64)  live 5-6          lr [72,+16K) zero 4, atomics 5, read 7
//   P  [0,32)   written 6 (xb/Wt/QK dead), read 7
// =====================================================================
extern "C" void kernel_launch(void* const* d_in, const int* in_sizes, int n_in,
                              void* d_out, int out_size, void* d_ws, size_t ws_size,
                              hipStream_t stream)
{
    (void)in_sizes; (void)n_in; (void)out_size; (void)ws_size;
    const float* x  = (const float*)d_in[0];
    const float* Wq = (const float*)d_in[1];
    const float* Wk = (const float*)d_in[2];
    const float* Wv = (const float*)d_in[3];
    float* out = (float*)d_out;
    char* ws = (char*)d_ws;

    u16* xb  = (u16*)(ws);                              //  8 MiB
    u16* Wt  = (u16*)(ws + ((size_t)8  << 20));         //  6 MiB
    u16* QK  = (u16*)(ws + ((size_t)14 << 20));         // 16 MiB [4096][2048]
    u16* Sb  = (u16*)(ws + ((size_t)32 << 20));         // 32 MiB [4096][4096]
    u16* Vt  = (u16*)(ws + ((size_t)64 << 20));         //  8 MiB [1024][4096]
    float* lr = (float*)(ws + ((size_t)72 << 20));      // 16 KiB row sums
    u16* P   = (u16*)(ws);                              // 32 MiB: 4 x [4096][1024]

    const int S = 4096, D = 1024;
    dim3 tb(32, 8);

    // 1) cast x to fp16
    cast_to_f16<<<(S * D) / (4 * 256), 256, 0, stream>>>(x, xb, S * D);

    // 2) transpose-cast all three W's into packed Wt[3072][1024]
    transpose_w3<<<dim3(32, 32, 3), tb, 0, stream>>>(Wq, Wk, Wv, Wt);

    // 3) [Q|K] = x @ [Wq|Wk], V^T written directly (M=4096, N=3072, K=1024)
    //    grid 12x16=192 blocks; panels: bnW=3, bmW=8, numPanelX=4
    gemm_bt<2><<<dim3(12, 16, 1), 512, 0, stream>>>(
        xb, D, Wt, D, QK, 2048, D, 1.0f, 0, 3, 8, 4, nullptr, Vt);

    // 4) zero row-sum accumulator
    zero_f32<<<S / (4 * 256), 256, 0, stream>>>(lr, S);

    // 5) Sb = exp((Q @ K^T)/32) + rowsum atomics  (M=N=4096, K=1024)
    //    grid 16x16=256 blocks; panels: bnW=4, bmW=8, numPanelX=4
    gemm_bt<1><<<dim3(16, 16, 1), 512, 0, stream>>>(
        QK, 2048, QK + 1024, 2048, Sb, S, D, 0.03125f, 0, 4, 8, 4, lr, nullptr);

    // 6) P[z] = expS @ V, split-K=4 (M=4096, N=1024, Ksplit=1024)
    //    grid 4x16x4; panels per z: bnW=1, bmW=8, numPanelX=4
    gemm_bt<0><<<dim3(4, 16, 4), 512, 0, stream>>>(
        Sb, S, Vt, S, P, D, 1024, 1.0f, (size_t)S * D, 1, 8, 4, nullptr, nullptr);

    // 7) out = (P0+P1+P2+P3) / l[row]
    add_div4<<<(S * D) / (8 * 256), 256, 0, stream>>>(P, lr, out);
}

// Round 2
// 214.337 us; speedup vs baseline: 1.0444x; 1.0244x over previous
//
#include <hip/hip_runtime.h>

typedef _Float16 f16x8 __attribute__((ext_vector_type(8)));
typedef float f32x4 __attribute__((ext_vector_type(4)));
typedef unsigned short u16;
typedef u16 u16x8 __attribute__((ext_vector_type(8)));
typedef u16 u16x4 __attribute__((ext_vector_type(4)));

// ---------- fp16 <-> fp32 helpers ----------
__device__ __forceinline__ u16 f2h_bits(float f) {
    _Float16 h = (_Float16)f;           // RNE
    return __builtin_bit_cast(u16, h);
}
__device__ __forceinline__ float h2f(u16 b) {
    return (float)__builtin_bit_cast(_Float16, b);
}

// async global->LDS, 16B per lane. LDS dest is wave-uniform base + lane*16;
// we pass per-thread t*16 which is exactly that layout.
typedef __attribute__((address_space(1))) unsigned int gu32_as1;
typedef __attribute__((address_space(3))) unsigned int lu32_as3;
__device__ __forceinline__ void gload16(const u16* g, u16* l) {
    __builtin_amdgcn_global_load_lds((gu32_as1*)g, (lu32_as3*)l, 16, 0, 0);
}

// =====================================================================
// GEMM: C[M,N] = alpha * A[M,K] * Bt[N,K]^T  (fp16 bits, k-contiguous).
//
// 256x256 tile, BK=64, 512 threads = 8 waves (2M x 4N), each wave owns a
// 128x64 C-tile = acc[8][4] f32x4 via mfma_f32_16x16x32_f16.
//
// TWO-BARRIER K-TILE (round-1 post-mortem: 8 lockstep phases serialized
// LDS reads against MFMA -> 23% MfmaUtil; the lever is the fine
// ds_read||MFMA overlap, not phase count):
//   top:  issue ALL 24 ds_read_b128 (order bfA, af0, bfB, af1); compiler
//         inserts counted lgkmcnt so Q(0,0) starts after first 12 land
//         and overlaps the rest of the read drain.
//   Q(0,0) Q(0,1) MFMAs (af0 x {bfA,bfB})
//   lgkmcnt(0); BARRIER 1  <- all waves' reads of buf complete -> buf dead
//   stage tiles kt+2 -> buf (8 global_load_lds)
//   Q(1,0) Q(1,1) MFMAs (af1 x {bfA,bfB})  -- pure-register, no LDS reads:
//         load issue hides under them; LDS pipe absorbs staging writes.
//   vmcnt(8) (tile kt+1's loads complete; kt+2's stay in flight); BARRIER 2
//   next iteration's read burst overlaps Q(1,x) matrix-pipe drain.
//
// LDS (128 KiB): per matrix [buf:2][half:2][seg-grp i:2][row:128][slot:4][8]
// u16 strides: buf 16384, half 8192, i 4096, row 32, slot 8.
// Swizzle (proven 0-conflict): slot s' at row r holds global seg
// s'^((r>>1)&3) (+4i). global_load_lds writes linearly at t*8 u16; the
// per-lane GLOBAL address is pre-swizzled: seg = (t&3)^((t>>3)&3) (+4i).
// Fragment read: row l16 (+16*mi), slot quad^((l16>>1)&3), region kk.
//
// MODE: 0 plain store; 1 exp(alpha*s)+rowsum atomics; 2 QKV (bn<8 -> QK
// ldc=2048; bn>=8 -> V transposed into vt[1024][4096]).
// Requires Ksplit % 64 == 0, Ksplit/64 >= 2. gridDim.z = split-K.
// =====================================================================
template <int MODE>
__global__ __launch_bounds__(512, 2) void gemm_bt(
    const u16* __restrict__ A, int lda,
    const u16* __restrict__ B, int ldb,
    u16* __restrict__ C, int ldc,
    int Ksplit, float alpha, size_t c_z_stride,
    int bnW, int bmW, int numPanelX,
    float* __restrict__ rowsum, u16* __restrict__ vt)
{
    __shared__ __attribute__((aligned(16))) u16 As[32768];  // 64 KB
    __shared__ __attribute__((aligned(16))) u16 Bs[32768];  // 64 KB

    const int t    = threadIdx.x;        // 0..511
    const int lane = t & 63;
    const int wave = t >> 6;             // 0..7
    const int wm   = wave >> 2;          // 0..1
    const int wn   = wave & 3;           // 0..3
    const int l16  = lane & 15;
    const int quad = lane >> 4;

    // 2D-panel XCD mapping (grid x*y divisible by 8)
    const int lin = blockIdx.y * gridDim.x + blockIdx.x;
    const int xcd = lin & 7;
    const int idx = lin >> 3;
    const int px  = xcd % numPanelX;
    const int py  = xcd / numPanelX;
    const int bn  = px * bnW + idx % bnW;
    const int bm  = py * bmW + idx / bnW;

    const int kz = blockIdx.z;
    A += (size_t)kz * Ksplit;
    B += (size_t)kz * Ksplit;
    C += (size_t)kz * c_z_stride;

    // staging: thread t -> row t>>2 of each 128-row half, LDS slot t&3,
    // global seg pre-swizzled so the linear LDS write lands swizzled.
    const int srow = t >> 2;
    const int sseg = (t & 3) ^ ((t >> 3) & 3);

    const u16* gA = A + (size_t)(bm * 256 + srow) * lda + sseg * 8;
    const u16* gB = B + (size_t)(bn * 256 + srow) * ldb + sseg * 8;
    const size_t a128 = (size_t)128 * lda;
    const size_t b128 = (size_t)128 * ldb;

    u16* lA = As + t * 8;
    u16* lB = Bs + t * 8;

#define STAGE_A(bufv, kt) do {                                   \
        const u16* _g = gA + (size_t)(kt) * 64;                  \
        u16* _l = lA + (bufv) * 16384;                           \
        gload16(_g,             _l);                             \
        gload16(_g + 32,        _l + 4096);                      \
        gload16(_g + a128,      _l + 8192);                      \
        gload16(_g + a128 + 32, _l + 12288);                     \
    } while (0)
#define STAGE_B(bufv, kt) do {                                   \
        const u16* _g = gB + (size_t)(kt) * 64;                  \
        u16* _l = lB + (bufv) * 16384;                           \
        gload16(_g,             _l);                             \
        gload16(_g + 32,        _l + 4096);                      \
        gload16(_g + b128,      _l + 8192);                      \
        gload16(_g + b128 + 32, _l + 12288);                     \
    } while (0)

    // fragment base pointers
    const int fslot = quad ^ ((l16 >> 1) & 3);
    const u16* Afr = As + wm * 8192 + l16 * 32 + fslot * 8;
    const u16* Bfr = Bs + (wn >> 1) * 8192 + (wn & 1) * 2048 + l16 * 32 + fslot * 8;

    f32x4 acc[8][4] = {};

    const int NT = Ksplit >> 6;

    // prologue: stage tiles 0 and 1 (8 loads each), wait for tile 0 only
    STAGE_A(0, 0); STAGE_B(0, 0);
    STAGE_A(1, 1); STAGE_B(1, 1);
    asm volatile("s_waitcnt vmcnt(8)" ::: "memory");
    __builtin_amdgcn_sched_barrier(0);
    __builtin_amdgcn_s_barrier();
    __builtin_amdgcn_sched_barrier(0);

    for (int kt = 0; kt < NT; ++kt) {
        const int buf = kt & 1;
        const u16* Af = Afr + buf * 16384;
        const u16* Bf = Bfr + buf * 16384;

        // ---- read burst: all 24 ds_read_b128, consumption order ----
        f16x8 bfA[2][2], bfB[2][2], af0[4][2], af1[4][2];
#pragma unroll
        for (int nj = 0; nj < 2; nj++)
#pragma unroll
            for (int kk = 0; kk < 2; kk++)
                bfA[nj][kk] = *(const f16x8*)(Bf + kk * 4096 + nj * 512);
#pragma unroll
        for (int mi = 0; mi < 4; mi++)
#pragma unroll
            for (int kk = 0; kk < 2; kk++)
                af0[mi][kk] = *(const f16x8*)(Af + kk * 4096 + mi * 512);
#pragma unroll
        for (int nj = 0; nj < 2; nj++)
#pragma unroll
            for (int kk = 0; kk < 2; kk++)
                bfB[nj][kk] = *(const f16x8*)(Bf + kk * 4096 + (2 + nj) * 512);
#pragma unroll
        for (int mi = 0; mi < 4; mi++)
#pragma unroll
            for (int kk = 0; kk < 2; kk++)
                af1[mi][kk] = *(const f16x8*)(Af + kk * 4096 + (4 + mi) * 512);

        // ---- Q(0,0) + Q(0,1): af0 x {bfA,bfB} ----
        __builtin_amdgcn_s_setprio(1);
#pragma unroll
        for (int mi = 0; mi < 4; mi++)
#pragma unroll
            for (int nj = 0; nj < 2; nj++)
#pragma unroll
                for (int kk = 0; kk < 2; kk++)
                    acc[mi][nj] = __builtin_amdgcn_mfma_f32_16x16x32_f16(
                        af0[mi][kk], bfA[nj][kk], acc[mi][nj], 0, 0, 0);
#pragma unroll
        for (int mi = 0; mi < 4; mi++)
#pragma unroll
            for (int nj = 0; nj < 2; nj++)
#pragma unroll
                for (int kk = 0; kk < 2; kk++)
                    acc[mi][2 + nj] = __builtin_amdgcn_mfma_f32_16x16x32_f16(
                        af0[mi][kk], bfB[nj][kk], acc[mi][2 + nj], 0, 0, 0);
        __builtin_amdgcn_s_setprio(0);

        // all this-wave ds_reads complete before barrier arrival ->
        // after BARRIER 1, buf is dead on every wave: safe to restage.
        asm volatile("s_waitcnt lgkmcnt(0)" ::: "memory");
        __builtin_amdgcn_sched_barrier(0);
        __builtin_amdgcn_s_barrier();
        __builtin_amdgcn_sched_barrier(0);

        // ---- stage tiles kt+2 into buf; overlap with Q(1,x) MFMAs ----
        if (kt + 2 < NT) { STAGE_A(buf, kt + 2); STAGE_B(buf, kt + 2); }

        // ---- Q(1,0) + Q(1,1): af1 x {bfA,bfB}, pure-register ----
        __builtin_amdgcn_s_setprio(1);
#pragma unroll
        for (int mi = 0; mi < 4; mi++)
#pragma unroll
            for (int nj = 0; nj < 2; nj++)
#pragma unroll
                for (int kk = 0; kk < 2; kk++)
                    acc[4 + mi][nj] = __builtin_amdgcn_mfma_f32_16x16x32_f16(
                        af1[mi][kk], bfA[nj][kk], acc[4 + mi][nj], 0, 0, 0);
#pragma unroll
        for (int mi = 0; mi < 4; mi++)
#pragma unroll
            for (int nj = 0; nj < 2; nj++)
#pragma unroll
                for (int kk = 0; kk < 2; kk++)
                    acc[4 + mi][2 + nj] = __builtin_amdgcn_mfma_f32_16x16x32_f16(
                        af1[mi][kk], bfB[nj][kk], acc[4 + mi][2 + nj], 0, 0, 0);
        __builtin_amdgcn_s_setprio(0);

        // tile kt+1's 8 loads complete; tile kt+2's 8 stay in flight
        if (kt < NT - 2)       asm volatile("s_waitcnt vmcnt(8)" ::: "memory");
        else if (kt == NT - 2) asm volatile("s_waitcnt vmcnt(0)" ::: "memory");
        __builtin_amdgcn_sched_barrier(0);
        __builtin_amdgcn_s_barrier();
        __builtin_amdgcn_sched_barrier(0);
    }
#undef STAGE_A
#undef STAGE_B

    // epilogue: C/D layout col = lane&15, row = quad*4 + reg
    const int crow = bm * 256 + wm * 128 + quad * 4;
    const int ccol = bn * 256 + wn * 64 + l16;

    if (MODE == 1) {
        float rs[8][4];
#pragma unroll
        for (int mi = 0; mi < 8; mi++)
#pragma unroll
            for (int r = 0; r < 4; r++) rs[mi][r] = 0.f;
#pragma unroll
        for (int mi = 0; mi < 8; mi++) {
#pragma unroll
            for (int ni = 0; ni < 4; ni++) {
#pragma unroll
                for (int r = 0; r < 4; r++) {
                    float e = __expf(acc[mi][ni][r] * alpha);
                    rs[mi][r] += e;
                    C[(size_t)(crow + mi * 16 + r) * ldc + (ccol + ni * 16)] = f2h_bits(e);
                }
            }
        }
#pragma unroll
        for (int mi = 0; mi < 8; mi++) {
#pragma unroll
            for (int r = 0; r < 4; r++) {
                float s = rs[mi][r];
#pragma unroll
                for (int o = 1; o < 16; o <<= 1) s += __shfl_xor(s, o);
                if (l16 == 0)
                    atomicAdd(&rowsum[crow + mi * 16 + r], s);
            }
        }
    } else if (MODE == 2 && bn >= 8) {
        // V tile -> write transposed into vt[1024][4096]
#pragma unroll
        for (int ni = 0; ni < 4; ni++) {
            const int cV = (bn - 8) * 256 + wn * 64 + ni * 16 + l16;
#pragma unroll
            for (int mi = 0; mi < 8; mi++) {
                u16x4 o;
#pragma unroll
                for (int r = 0; r < 4; r++) o[r] = f2h_bits(acc[mi][ni][r]);
                *(u16x4*)(vt + (size_t)cV * 4096 + crow + mi * 16) = o;
            }
        }
    } else {
#pragma unroll
        for (int mi = 0; mi < 8; mi++)
#pragma unroll
            for (int ni = 0; ni < 4; ni++)
#pragma unroll
                for (int r = 0; r < 4; r++)
                    C[(size_t)(crow + mi * 16 + r) * ldc + (ccol + ni * 16)] =
                        f2h_bits(acc[mi][ni][r] * alpha);
    }
}

// =====================================================================
// cast fp32 -> fp16 bits, 4 elems/thread
// =====================================================================
__global__ __launch_bounds__(256) void cast_to_f16(
    const float* __restrict__ in, u16* __restrict__ out, int n)
{
    int i = (blockIdx.x * 256 + threadIdx.x) * 4;
    if (i + 3 < n) {
        float4 v = *(const float4*)(in + i);
        ushort4 o;
        o.x = f2h_bits(v.x);
        o.y = f2h_bits(v.y);
        o.z = f2h_bits(v.z);
        o.w = f2h_bits(v.w);
        *(ushort4*)(out + i) = o;
    }
}

// =====================================================================
// transpose the 3 weight matrices [1024][1024] fp32 -> packed fp16
// Wt[3072][1024]; z selects the matrix. 32x32 LDS tile, block (32,8).
// =====================================================================
__global__ __launch_bounds__(256) void transpose_w3(
    const float* __restrict__ W0, const float* __restrict__ W1,
    const float* __restrict__ W2, u16* __restrict__ out)
{
    const float* in = (blockIdx.z == 0) ? W0 : (blockIdx.z == 1) ? W1 : W2;
    u16* o = out + (size_t)blockIdx.z * 1024 * 1024;
    __shared__ float tile[32][33];
    const int bx = blockIdx.x * 32;
    const int by = blockIdx.y * 32;
    const int tx = threadIdx.x, ty = threadIdx.y;
#pragma unroll
    for (int j = 0; j < 4; j++)
        tile[ty + j * 8][tx] = in[(size_t)(by + ty + j * 8) * 1024 + bx + tx];
    __syncthreads();
#pragma unroll
    for (int j = 0; j < 4; j++)
        o[(size_t)(bx + ty + j * 8) * 1024 + by + tx] = f2h_bits(tile[tx][ty + j * 8]);
}

// =====================================================================
// zero a float array (n multiple of 1024)
// =====================================================================
__global__ __launch_bounds__(256) void zero_f32(float* __restrict__ p, int n)
{
    int i = (blockIdx.x * 256 + threadIdx.x) * 4;
    if (i + 3 < n) *(float4*)(p + i) = float4{0.f, 0.f, 0.f, 0.f};
}

// =====================================================================
// out = (P0+P1+P2+P3)/l[row]; partials fp16, 8 elems/thread
// =====================================================================
__global__ __launch_bounds__(256) void add_div4(
    const u16* __restrict__ P, const float* __restrict__ l,
    float* __restrict__ o)
{
    const size_t zs = (size_t)4096 * 1024;
    int i = (blockIdx.x * 256 + threadIdx.x) * 8;
    float inv = 1.0f / l[i >> 10];
    float s[8] = {};
#pragma unroll
    for (int z = 0; z < 4; z++) {
        u16x8 h = *(const u16x8*)(P + z * zs + i);
#pragma unroll
        for (int j = 0; j < 8; j++) s[j] += h2f(h[j]);
    }
    float4 lo{s[0] * inv, s[1] * inv, s[2] * inv, s[3] * inv};
    float4 hi{s[4] * inv, s[5] * inv, s[6] * inv, s[7] * inv};
    *(float4*)(o + i) = lo;
    *(float4*)(o + i + 4) = hi;
}

// =====================================================================
// launch
//
// Workspace liveness (MiB):
//   xb [0,8)    live 1-3          Wt [8,14)  live 2-3
//   QK [14,30)  live 3-5          Vt [64,72) live 3-6
//   Sb [32,64)  live 5-6          lr [72,+16K) zero 4, atomics 5, read 7
//   P  [0,32)   written 6 (xb/Wt/QK dead), read 7
// =====================================================================
extern "C" void kernel_launch(void* const* d_in, const int* in_sizes, int n_in,
                              void* d_out, int out_size, void* d_ws, size_t ws_size,
                              hipStream_t stream)
{
    (void)in_sizes; (void)n_in; (void)out_size; (void)ws_size;
    const float* x  = (const float*)d_in[0];
    const float* Wq = (const float*)d_in[1];
    const float* Wk = (const float*)d_in[2];
    const float* Wv = (const float*)d_in[3];
    float* out = (float*)d_out;
    char* ws = (char*)d_ws;

    u16* xb  = (u16*)(ws);                              //  8 MiB
    u16* Wt  = (u16*)(ws + ((size_t)8  << 20));         //  6 MiB
    u16* QK  = (u16*)(ws + ((size_t)14 << 20));         // 16 MiB [4096][2048]
    u16* Sb  = (u16*)(ws + ((size_t)32 << 20));         // 32 MiB [4096][4096]
    u16* Vt  = (u16*)(ws + ((size_t)64 << 20));         //  8 MiB [1024][4096]
    float* lr = (float*)(ws + ((size_t)72 << 20));      // 16 KiB row sums
    u16* P   = (u16*)(ws);                              // 32 MiB: 4 x [4096][1024]

    const int S = 4096, D = 1024;
    dim3 tb(32, 8);

    // 1) cast x to fp16
    cast_to_f16<<<(S * D) / (4 * 256), 256, 0, stream>>>(x, xb, S * D);

    // 2) transpose-cast all three W's into packed Wt[3072][1024]
    transpose_w3<<<dim3(32, 32, 3), tb, 0, stream>>>(Wq, Wk, Wv, Wt);

    // 3) [Q|K] = x @ [Wq|Wk], V^T written directly (M=4096, N=3072, K=1024)
    //    grid 12x16=192 blocks; panels: bnW=3, bmW=8, numPanelX=4
    gemm_bt<2><<<dim3(12, 16, 1), 512, 0, stream>>>(
        xb, D, Wt, D, QK, 2048, D, 1.0f, 0, 3, 8, 4, nullptr, Vt);

    // 4) zero row-sum accumulator
    zero_f32<<<S / (4 * 256), 256, 0, stream>>>(lr, S);

    // 5) Sb = exp((Q @ K^T)/32) + rowsum atomics  (M=N=4096, K=1024)
    //    grid 16x16=256 blocks; panels: bnW=4, bmW=8, numPanelX=4
    gemm_bt<1><<<dim3(16, 16, 1), 512, 0, stream>>>(
        QK, 2048, QK + 1024, 2048, Sb, S, D, 0.03125f, 0, 4, 8, 4, lr, nullptr);

    // 6) P[z] = expS @ V, split-K=4 (M=4096, N=1024, Ksplit=1024)
    //    grid 4x16x4; panels per z: bnW=1, bmW=8, numPanelX=4
    gemm_bt<0><<<dim3(4, 16, 4), 512, 0, stream>>>(
        Sb, S, Vt, S, P, D, 1024, 1.0f, (size_t)S * D, 1, 8, 4, nullptr, nullptr);

    // 7) out = (P0+P1+P2+P3) / l[row]
    add_div4<<<(S * D) / (8 * 256), 256, 0, stream>>>(P, lr, out);
}